// Round 11
// baseline (20.756 us; speedup 1.0000x reference)
//
#include <hip/hip_runtime.h>
#include <hip/hip_bf16.h>

// R11: TWO waves per sample (2048 blocks x 128 threads), ONE barrier.
// Wave w handles tiles t = w, w+2, w+4, w+6 (interleaved -> balanced halves).
// Per tile: block-private per-wave 95-bin LDS histogram + 10-bit packed binary
// ones-counts + cont colsum(relu(X@W_cont+b)) via mfma_f32_16x16x32_bf16.
// After one __syncthreads, wave 0 alone runs the whole epilogue (merge 2 waves'
// partials, bin weights, 101-row embedding matvec + W1 via readlane bcast,
// W2 butterfly); wave 1 exits immediately.
// Rationale vs R10 (1 wave/sample, 19.8us): 4096 waves -> 4/SIMD latency
// hiding, and per-wave long pole halves (8 -> 4 tiles). vs R6-8: only one
// barrier and no multi-wave epilogue coupling.

#define CARD3 11
#define CARD4 19
#define CARD5 31
#define CARD6 34

typedef __attribute__((ext_vector_type(8))) short bf16x8;
typedef __attribute__((ext_vector_type(4))) float f32x4;
typedef __attribute__((ext_vector_type(4))) unsigned uintx4;
typedef int   int4a  __attribute__((ext_vector_type(4), aligned(4)));
typedef int   int2a  __attribute__((ext_vector_type(2), aligned(4)));
typedef float flt4a  __attribute__((ext_vector_type(4), aligned(4)));

static __device__ __forceinline__ unsigned pk_bf16(float a, float b) {
    unsigned ua = __float_as_uint(a), ub = __float_as_uint(b);
    ua += 0x7FFFu + ((ua >> 16) & 1u);      // round-to-nearest-even
    ub += 0x7FFFu + ((ub >> 16) & 1u);
    return ((ua >> 16) & 0xFFFFu) | (ub & 0xFFFF0000u);
}

static __device__ __forceinline__ float rdlane(float v, int i) {
    return __builtin_bit_cast(float,
        __builtin_amdgcn_readlane(__builtin_bit_cast(int, v), i));
}

__global__ __launch_bounds__(128) void mlp_wave2(
    const float* __restrict__ cont_x,   // [B,S,5]
    const int*   __restrict__ cat_x,    // [B,S,7]
    const int*   __restrict__ length,   // [B]
    const float* __restrict__ e0, const float* __restrict__ e1,
    const float* __restrict__ e2, const float* __restrict__ e3,
    const float* __restrict__ e4, const float* __restrict__ e5,
    const float* __restrict__ e6,
    const float* __restrict__ W_cont,   // [5,64]
    const float* __restrict__ b_cont,   // [64]
    const float* __restrict__ W1,       // [128,64]
    const float* __restrict__ b1,       // [64]
    const float* __restrict__ W2,       // [64,2]
    const float* __restrict__ b2,       // [2]
    float*       __restrict__ out,      // [B,2]
    int S)
{
    constexpr int HOFF[4] = {0, 11, 30, 61};
    constexpr int CARD[7] = {2, 2, 2, CARD3, CARD4, CARD5, CARD6};
    constexpr int OFFB[7] = {0, 2, 4, 6, 17, 36, 67};

    __shared__ int   hist[2][96];
    __shared__ int   bc_s[2];
    __shared__ float pcont[2][64];

    const int b    = blockIdx.x;
    const int tid  = threadIdx.x;
    const int wv   = tid >> 6;          // wave 0 or 1
    const int l    = tid & 63;
    const int lo16 = l & 15;
    const bool lo  = (l < 16);

    const int*   cat7  = cat_x  + (size_t)b * S * 7;
    const float* cont5 = cont_x + (size_t)b * S * 5;

    // ping-pong staging registers (explicit names, rule #20)
    int4a caA = {0,0,0,0}, caB = {0,0,0,0};
    int2a cbA = {0,0},     cbB = {0,0};
    int   ccA = 0,         ccB = 0;
    flt4a xaA = {0,0,0,0}, xaB = {0,0,0,0};
    float xbA = 0.f,       xbB = 0.f;

#define LOADA(T) do { const int* cp_ = cat7 + (size_t)((T)*64 + l) * 7;          \
        caA = *(const int4a*)cp_; cbA = *(const int2a*)(cp_ + 4); ccA = cp_[6];  \
        const float* xp_ = cont5 + (size_t)((T)*64 + l) * 5;                     \
        xaA = *(const flt4a*)xp_; xbA = xp_[4]; } while (0)
#define LOADB(T) do { const int* cp_ = cat7 + (size_t)((T)*64 + l) * 7;          \
        caB = *(const int4a*)cp_; cbB = *(const int2a*)(cp_ + 4); ccB = cp_[6];  \
        const float* xp_ = cont5 + (size_t)((T)*64 + l) * 5;                     \
        xaB = *(const flt4a*)xp_; xbB = xp_[4]; } while (0)

    // issue tile-t0 loads immediately: address-safe for any len (row < 128 < S)
    const int t0 = wv;
    LOADA(t0);

    const int len = length[b];          // uniform s_load, overlaps t0 loads
    const int nt  = (len + 63) >> 6;    // 1..8 tiles total
    const int t1  = wv + 2, t2 = wv + 4, t3 = wv + 6;

    // zero own wave's private histogram (same-wave DS ordering, no barrier)
    hist[wv][l] = 0;
    if (l < 32) hist[wv][64 + l] = 0;

    // ---- B-frags: staged coalesced + shfl ----
    unsigned q0, q1, q2;
    {
        const float w0 = W_cont[l],        w1 = W_cont[64 + l];
        const float w2 = W_cont[128 + l],  w3 = W_cont[192 + l];
        const float w4 = W_cont[256 + l],  w5 = b_cont[l];
        q0 = pk_bf16(w0, w1); q1 = pk_bf16(w2, w3); q2 = pk_bf16(w4, w5);
    }
    bf16x8 Bf[4];
#pragma unroll
    for (int ntc = 0; ntc < 4; ++ntc) {
        const int src = ntc * 16 + lo16;
        unsigned c0 = (unsigned)__shfl((int)q0, src);
        unsigned c1 = (unsigned)__shfl((int)q1, src);
        unsigned c2 = (unsigned)__shfl((int)q2, src);
        c0 = lo ? c0 : 0u; c1 = lo ? c1 : 0u; c2 = lo ? c2 : 0u;
        const uintx4 bu = {c0, c1, c2, 0u};
        Bf[ntc] = __builtin_bit_cast(bf16x8, bu);
    }

    int   c1pack = 0;                       // 3x 10-bit packed ones-counts
    f32x4 sum0 = {0.f, 0.f, 0.f, 0.f};
    f32x4 sum1 = sum0, sum2 = sum0, sum3 = sum0;
    const f32x4 z = {0.f, 0.f, 0.f, 0.f};

    auto COMPUTE = [&](int base, const int4a& ca, const int2a& cb, int cc,
                       const flt4a& xa, float xb) {
        const bool valid = (base + l < len);
        float x0 = 0.f, x1 = 0.f, x2 = 0.f, x3 = 0.f, x4 = 0.f;
        if (valid) {
            c1pack += ca.x + (ca.y << 10) + (ca.z << 20);
            atomicAdd(&hist[wv][HOFF[0] + ca.w], 1);
            atomicAdd(&hist[wv][HOFF[1] + cb.x], 1);
            atomicAdd(&hist[wv][HOFF[2] + cb.y], 1);
            atomicAdd(&hist[wv][HOFF[3] + cc],   1);
            x0 = xa.x; x1 = xa.y; x2 = xa.z; x3 = xa.w; x4 = xb;
        }
        const float aug = valid ? 1.0f : 0.0f;
        const unsigned p0 = pk_bf16(x0, x1);
        const unsigned p1 = pk_bf16(x2, x3);
        const unsigned p2 = pk_bf16(x4, aug);

#pragma unroll
        for (int t4 = 0; t4 < 4; ++t4) {
            const int src = t4 * 16 + lo16;
            unsigned a0 = (unsigned)__shfl((int)p0, src);
            unsigned a1 = (unsigned)__shfl((int)p1, src);
            unsigned a2 = (unsigned)__shfl((int)p2, src);
            a0 = lo ? a0 : 0u; a1 = lo ? a1 : 0u; a2 = lo ? a2 : 0u;
            const uintx4 au = {a0, a1, a2, 0u};
            const bf16x8 Af = __builtin_bit_cast(bf16x8, au);

            const f32x4 d0 = __builtin_amdgcn_mfma_f32_16x16x32_bf16(Af, Bf[0], z, 0, 0, 0);
            const f32x4 d1 = __builtin_amdgcn_mfma_f32_16x16x32_bf16(Af, Bf[1], z, 0, 0, 0);
            const f32x4 d2 = __builtin_amdgcn_mfma_f32_16x16x32_bf16(Af, Bf[2], z, 0, 0, 0);
            const f32x4 d3 = __builtin_amdgcn_mfma_f32_16x16x32_bf16(Af, Bf[3], z, 0, 0, 0);
#pragma unroll
            for (int i = 0; i < 4; ++i) {
                sum0[i] += fmaxf(d0[i], 0.f);
                sum1[i] += fmaxf(d1[i], 0.f);
                sum2[i] += fmaxf(d2[i], 0.f);
                sum3[i] += fmaxf(d3[i], 0.f);
            }
        }
    };

    // ---- pipelined tile sequence: t0, t1, t2, t3 (wave-uniform gating) ----
    if (t0 < nt) {
        if (t1 < nt) LOADB(t1);
        COMPUTE(t0 * 64, caA, cbA, ccA, xaA, xbA);
        if (t1 < nt) {
            if (t2 < nt) LOADA(t2);
            COMPUTE(t1 * 64, caB, cbB, ccB, xaB, xbB);
            if (t2 < nt) {
                if (t3 < nt) LOADB(t3);
                COMPUTE(t2 * 64, caA, cbA, ccA, xaA, xbA);
                if (t3 < nt) COMPUTE(t3 * 64, caB, cbB, ccB, xaB, xbB);
            }
        }
    }
#undef LOADA
#undef LOADB

    // ---- per-wave reductions -> LDS partials ----
#pragma unroll
    for (int off = 1; off <= 32; off <<= 1) c1pack += __shfl_xor(c1pack, off);
    if (l == 0) bc_s[wv] = c1pack;

    float s0 = sum0[0] + sum0[1] + sum0[2] + sum0[3];
    float s1 = sum1[0] + sum1[1] + sum1[2] + sum1[3];
    float s2 = sum2[0] + sum2[1] + sum2[2] + sum2[3];
    float s3 = sum3[0] + sum3[1] + sum3[2] + sum3[3];
    s0 += __shfl_xor(s0, 16); s0 += __shfl_xor(s0, 32);
    s1 += __shfl_xor(s1, 16); s1 += __shfl_xor(s1, 32);
    s2 += __shfl_xor(s2, 16); s2 += __shfl_xor(s2, 32);
    s3 += __shfl_xor(s3, 16); s3 += __shfl_xor(s3, 32);
    if (lo) {
        pcont[wv][lo16]      = s0;
        pcont[wv][16 + lo16] = s1;
        pcont[wv][32 + lo16] = s2;
        pcont[wv][48 + lo16] = s3;
    }
    __syncthreads();                       // the ONE barrier

    if (tid >= 64) return;                 // wave 1 done

    // ================= wave-0-only epilogue =================
    const float inv_len = 1.0f / (float)len;
    const float inv7    = inv_len * (1.0f / 7.0f);

    // cont mean, lane = dim
    const float cmean = (pcont[0][l] + pcont[1][l]) * inv_len;

    // merged packed binary counts (10-bit fields, sums <= 512, no carry)
    const int c1pk = bc_s[0] + bc_s[1];

    // bin weights, lane-sliced: wA = bins 0..63, wB = bins 64..100
    float wA, wB;
    {
        const int j  = l >> 1;
        const int c1 = (c1pk >> (10 * j)) & 0x3FF;
        const float bw = (l & 1) ? (float)c1 : (float)(len - c1);
        wA = (l < 6)  ? bw * inv7
                      : (float)(hist[0][l - 6] + hist[1][l - 6]) * inv7;
        wB = (l < 37) ? (float)(hist[0][58 + l] + hist[1][58 + l]) * inv7 : 0.f;
    }

    // ---- 101-row weighted embedding matvec, lane = dim, readlane bcast ----
    float pa0 = 0.f, pa1 = 0.f, pa2 = 0.f, pa3 = 0.f;
    {
        int cnt = 0;
#pragma unroll
        for (int t = 0; t < 7; ++t) {
            const float* tab = (t == 0) ? e0 : (t == 1) ? e1 : (t == 2) ? e2
                             : (t == 3) ? e3 : (t == 4) ? e4 : (t == 5) ? e5 : e6;
#pragma unroll
            for (int v = 0; v < CARD[t]; ++v) {
                const int i = OFFB[t] + v;               // compile-time
                const float f = (i < 64) ? rdlane(wA, i) : rdlane(wB, i - 64);
                const float ev = tab[v * 64 + l];
                if ((cnt & 3) == 0)      pa0 = fmaf(f, ev, pa0);
                else if ((cnt & 3) == 1) pa1 = fmaf(f, ev, pa1);
                else if ((cnt & 3) == 2) pa2 = fmaf(f, ev, pa2);
                else                     pa3 = fmaf(f, ev, pa3);
                ++cnt;
            }
        }
    }
    const float pcv = (pa0 + pa1) + (pa2 + pa3);         // pooled cat dim l

    // ---- W1: h[l] = relu(b1 + sum_d pooled[d] * W1[d][l]) ----
    float h0 = b1[l], h1 = 0.f, h2 = 0.f, h3 = 0.f;
#pragma unroll
    for (int d = 0; d < 64; ++d) {
        const float f = rdlane(pcv, d);
        const float wvv = W1[d * 64 + l];
        if ((d & 3) == 0)      h0 = fmaf(f, wvv, h0);
        else if ((d & 3) == 1) h1 = fmaf(f, wvv, h1);
        else if ((d & 3) == 2) h2 = fmaf(f, wvv, h2);
        else                   h3 = fmaf(f, wvv, h3);
    }
#pragma unroll
    for (int d = 0; d < 64; ++d) {
        const float f = rdlane(cmean, d);
        const float wvv = W1[(64 + d) * 64 + l];
        if ((d & 3) == 0)      h0 = fmaf(f, wvv, h0);
        else if ((d & 3) == 1) h1 = fmaf(f, wvv, h1);
        else if ((d & 3) == 2) h2 = fmaf(f, wvv, h2);
        else                   h3 = fmaf(f, wvv, h3);
    }
    const float h = fmaxf((h0 + h1) + (h2 + h3), 0.f);

    // ---- W2 butterfly + store ----
    const float2 w2v = ((const float2*)W2)[l];
    float rr0 = h * w2v.x;
    float rr1 = h * w2v.y;
#pragma unroll
    for (int off = 1; off <= 32; off <<= 1) {
        rr0 += __shfl_xor(rr0, off);
        rr1 += __shfl_xor(rr1, off);
    }
    if (l == 0) {
        const float2 bb2 = *(const float2*)b2;
        float2 res;
        res.x = fmaxf(rr0 + bb2.x, 0.f);
        res.y = fmaxf(rr1 + bb2.y, 0.f);
        ((float2*)out)[b] = res;
    }
}

extern "C" void kernel_launch(void* const* d_in, const int* in_sizes, int n_in,
                              void* d_out, int out_size, void* d_ws, size_t ws_size,
                              hipStream_t stream)
{
    const float* cont_x = (const float*)d_in[0];
    const int*   cat_x  = (const int*)d_in[1];
    const int*   length = (const int*)d_in[2];
    const float* e0     = (const float*)d_in[3];
    const float* e1     = (const float*)d_in[4];
    const float* e2     = (const float*)d_in[5];
    const float* e3     = (const float*)d_in[6];
    const float* e4     = (const float*)d_in[7];
    const float* e5     = (const float*)d_in[8];
    const float* e6     = (const float*)d_in[9];
    const float* W_cont = (const float*)d_in[10];
    const float* b_cont = (const float*)d_in[11];
    const float* W1     = (const float*)d_in[12];
    const float* b1     = (const float*)d_in[13];
    const float* W2     = (const float*)d_in[14];
    const float* b2     = (const float*)d_in[15];
    float*       out    = (float*)d_out;

    const int B = in_sizes[2];                 // 2048
    const int S = in_sizes[0] / (B * 5);       // 512

    hipLaunchKernelGGL(mlp_wave2, dim3(B), dim3(128), 0, stream,
                       cont_x, cat_x, length,
                       e0, e1, e2, e3, e4, e5, e6,
                       W_cont, b_cont, W1, b1, W2, b2,
                       out, S);
}

// Round 12
// 18.514 us; speedup vs baseline: 1.1211x; 1.1211x over previous
//
#include <hip/hip_runtime.h>
#include <hip/hip_bf16.h>

// R12: ONE wave per sample (2048 blocks x 64 threads), zero barriers (= R10)
// with a restructured epilogue:
//  - W1 matvec: lane (s=l>>4, q=l&15) computes cols 4q..4q+3 over rows
//    d=32s..32s+31 with coalesced dwordx4 loads of W1 (32 VMEM instrs vs 128),
//    p[d] broadcast via padded LDS (bank-conflict-free, addr = 33s+i),
//    shfl_xor(16,32) reduce; b1/W2 vectorized; W2 butterfly xor 1,2,4,8.
//  - Embedding matvec unchanged (tables are 26KB, L1-hot).
// Main loop per tile (unchanged from R10): staged coalesced loads, 95-bin
// LDS-atomic histogram + 10-bit packed binary counts + cont
// colsum(relu(X@W_cont+b)) via mfma_f32_16x16x32_bf16, depth-2 ping-pong.

#define CARD3 11
#define CARD4 19
#define CARD5 31
#define CARD6 34

typedef __attribute__((ext_vector_type(8))) short bf16x8;
typedef __attribute__((ext_vector_type(4))) float f32x4;
typedef __attribute__((ext_vector_type(4))) unsigned uintx4;
typedef int   int4a  __attribute__((ext_vector_type(4), aligned(4)));
typedef int   int2a  __attribute__((ext_vector_type(2), aligned(4)));
typedef float flt4a  __attribute__((ext_vector_type(4), aligned(4)));

static __device__ __forceinline__ unsigned pk_bf16(float a, float b) {
    unsigned ua = __float_as_uint(a), ub = __float_as_uint(b);
    ua += 0x7FFFu + ((ua >> 16) & 1u);      // round-to-nearest-even
    ub += 0x7FFFu + ((ub >> 16) & 1u);
    return ((ua >> 16) & 0xFFFFu) | (ub & 0xFFFF0000u);
}

static __device__ __forceinline__ float rdlane(float v, int i) {
    return __builtin_bit_cast(float,
        __builtin_amdgcn_readlane(__builtin_bit_cast(int, v), i));
}

__global__ __launch_bounds__(64) void mlp_wave(
    const float* __restrict__ cont_x,   // [B,S,5]
    const int*   __restrict__ cat_x,    // [B,S,7]
    const int*   __restrict__ length,   // [B]
    const float* __restrict__ e0, const float* __restrict__ e1,
    const float* __restrict__ e2, const float* __restrict__ e3,
    const float* __restrict__ e4, const float* __restrict__ e5,
    const float* __restrict__ e6,
    const float* __restrict__ W_cont,   // [5,64]
    const float* __restrict__ b_cont,   // [64]
    const float* __restrict__ W1,       // [128,64]
    const float* __restrict__ b1,       // [64]
    const float* __restrict__ W2,       // [64,2]
    const float* __restrict__ b2,       // [2]
    float*       __restrict__ out,      // [B,2]
    int S)
{
    constexpr int HOFF[4] = {0, 11, 30, 61};
    constexpr int CARD[7] = {2, 2, 2, CARD3, CARD4, CARD5, CARD6};
    constexpr int OFFB[7] = {0, 2, 4, 6, 17, 36, 67};

    __shared__ int   hist[96];
    __shared__ float pcontl[64];
    __shared__ float pls[136];          // pooled[128] with +1 pad per 32 (addr = d + (d>>5))

    const int b    = blockIdx.x;
    const int l    = threadIdx.x;       // 0..63
    const int lo16 = l & 15;
    const bool lo  = (l < 16);

    const int len = length[b];          // uniform s_load
    const int nt  = (len + 63) >> 6;    // 1..8 tiles

    // zero block-private histogram (same-wave DS ordering)
    hist[l] = 0;
    if (l < 32) hist[64 + l] = 0;

    const int*   cat7  = cat_x  + (size_t)b * S * 7;
    const float* cont5 = cont_x + (size_t)b * S * 5;

    // ---- B-frags: staged coalesced + shfl ----
    unsigned q0, q1, q2;
    {
        const float w0 = W_cont[l],        w1 = W_cont[64 + l];
        const float w2 = W_cont[128 + l],  w3 = W_cont[192 + l];
        const float w4 = W_cont[256 + l],  w5 = b_cont[l];
        q0 = pk_bf16(w0, w1); q1 = pk_bf16(w2, w3); q2 = pk_bf16(w4, w5);
    }
    bf16x8 Bf[4];
#pragma unroll
    for (int ntc = 0; ntc < 4; ++ntc) {
        const int src = ntc * 16 + lo16;
        unsigned c0 = (unsigned)__shfl((int)q0, src);
        unsigned c1 = (unsigned)__shfl((int)q1, src);
        unsigned c2 = (unsigned)__shfl((int)q2, src);
        c0 = lo ? c0 : 0u; c1 = lo ? c1 : 0u; c2 = lo ? c2 : 0u;
        const uintx4 bu = {c0, c1, c2, 0u};
        Bf[ntc] = __builtin_bit_cast(bf16x8, bu);
    }

    int   c1pack = 0;                       // 3x 10-bit packed ones-counts
    f32x4 sum0 = {0.f, 0.f, 0.f, 0.f};
    f32x4 sum1 = sum0, sum2 = sum0, sum3 = sum0;
    const f32x4 z = {0.f, 0.f, 0.f, 0.f};

    // ping-pong staging registers (explicit names, rule #20)
    int4a caA = {0,0,0,0}, caB = {0,0,0,0};
    int2a cbA = {0,0},     cbB = {0,0};
    int   ccA = 0,         ccB = 0;
    flt4a xaA = {0,0,0,0}, xaB = {0,0,0,0};
    float xbA = 0.f,       xbB = 0.f;

#define LOADA(T) do { const int* cp_ = cat7 + (size_t)((T)*64 + l) * 7;          \
        caA = *(const int4a*)cp_; cbA = *(const int2a*)(cp_ + 4); ccA = cp_[6];  \
        const float* xp_ = cont5 + (size_t)((T)*64 + l) * 5;                     \
        xaA = *(const flt4a*)xp_; xbA = xp_[4]; } while (0)
#define LOADB(T) do { const int* cp_ = cat7 + (size_t)((T)*64 + l) * 7;          \
        caB = *(const int4a*)cp_; cbB = *(const int2a*)(cp_ + 4); ccB = cp_[6];  \
        const float* xp_ = cont5 + (size_t)((T)*64 + l) * 5;                     \
        xaB = *(const flt4a*)xp_; xbB = xp_[4]; } while (0)

    auto COMPUTE = [&](int base, const int4a& ca, const int2a& cb, int cc,
                       const flt4a& xa, float xb) {
        const bool valid = (base + l < len);
        float x0 = 0.f, x1 = 0.f, x2 = 0.f, x3 = 0.f, x4 = 0.f;
        if (valid) {
            c1pack += ca.x + (ca.y << 10) + (ca.z << 20);
            atomicAdd(&hist[HOFF[0] + ca.w], 1);
            atomicAdd(&hist[HOFF[1] + cb.x], 1);
            atomicAdd(&hist[HOFF[2] + cb.y], 1);
            atomicAdd(&hist[HOFF[3] + cc],   1);
            x0 = xa.x; x1 = xa.y; x2 = xa.z; x3 = xa.w; x4 = xb;
        }
        const float aug = valid ? 1.0f : 0.0f;
        const unsigned p0 = pk_bf16(x0, x1);
        const unsigned p1 = pk_bf16(x2, x3);
        const unsigned p2 = pk_bf16(x4, aug);

#pragma unroll
        for (int t4 = 0; t4 < 4; ++t4) {
            const int src = t4 * 16 + lo16;
            unsigned a0 = (unsigned)__shfl((int)p0, src);
            unsigned a1 = (unsigned)__shfl((int)p1, src);
            unsigned a2 = (unsigned)__shfl((int)p2, src);
            a0 = lo ? a0 : 0u; a1 = lo ? a1 : 0u; a2 = lo ? a2 : 0u;
            const uintx4 au = {a0, a1, a2, 0u};
            const bf16x8 Af = __builtin_bit_cast(bf16x8, au);

            const f32x4 d0 = __builtin_amdgcn_mfma_f32_16x16x32_bf16(Af, Bf[0], z, 0, 0, 0);
            const f32x4 d1 = __builtin_amdgcn_mfma_f32_16x16x32_bf16(Af, Bf[1], z, 0, 0, 0);
            const f32x4 d2 = __builtin_amdgcn_mfma_f32_16x16x32_bf16(Af, Bf[2], z, 0, 0, 0);
            const f32x4 d3 = __builtin_amdgcn_mfma_f32_16x16x32_bf16(Af, Bf[3], z, 0, 0, 0);
#pragma unroll
            for (int i = 0; i < 4; ++i) {
                sum0[i] += fmaxf(d0[i], 0.f);
                sum1[i] += fmaxf(d1[i], 0.f);
                sum2[i] += fmaxf(d2[i], 0.f);
                sum3[i] += fmaxf(d3[i], 0.f);
            }
        }
    };

    // ---- software-pipelined tile loop (wave-uniform branches) ----
    LOADA(0);
    if (nt > 1) LOADB(1);
#pragma unroll 1
    for (int t = 0; t < nt; t += 2) {
        COMPUTE(t * 64, caA, cbA, ccA, xaA, xbA);
        if (t + 2 < nt) LOADA(t + 2);
        if (t + 1 < nt) {
            COMPUTE((t + 1) * 64, caB, cbB, ccB, xaB, xbB);
            if (t + 3 < nt) LOADB(t + 3);
        }
    }
#undef LOADA
#undef LOADB

    // ---- intra-wave reductions ----
#pragma unroll
    for (int off = 1; off <= 32; off <<= 1) c1pack += __shfl_xor(c1pack, off);

    float s0 = sum0[0] + sum0[1] + sum0[2] + sum0[3];
    float s1 = sum1[0] + sum1[1] + sum1[2] + sum1[3];
    float s2 = sum2[0] + sum2[1] + sum2[2] + sum2[3];
    float s3 = sum3[0] + sum3[1] + sum3[2] + sum3[3];
    s0 += __shfl_xor(s0, 16); s0 += __shfl_xor(s0, 32);
    s1 += __shfl_xor(s1, 16); s1 += __shfl_xor(s1, 32);
    s2 += __shfl_xor(s2, 16); s2 += __shfl_xor(s2, 32);
    s3 += __shfl_xor(s3, 16); s3 += __shfl_xor(s3, 32);
    if (lo) {
        pcontl[lo16]      = s0;
        pcontl[16 + lo16] = s1;
        pcontl[32 + lo16] = s2;
        pcontl[48 + lo16] = s3;
    }

    const float inv_len = 1.0f / (float)len;
    const float inv7    = inv_len * (1.0f / 7.0f);

    // cont mean -> padded pooled LDS slot 64+l (same-wave LDS ordering)
    {
        const int d = 64 + l;
        pls[d + (d >> 5)] = pcontl[l] * inv_len;
    }

    // bin weights, lane-sliced: wA = bins 0..63, wB = bins 64..100
    float wA, wB;
    {
        const int j  = l >> 1;
        const int c1 = (c1pack >> (10 * j)) & 0x3FF;
        const float bw = (l & 1) ? (float)c1 : (float)(len - c1);
        wA = (l < 6) ? bw * inv7 : (float)hist[l - 6] * inv7;
        wB = (l < 37) ? (float)hist[58 + l] * inv7 : 0.f;
    }

    // ---- 101-row weighted embedding matvec, lane = dim (tables L1-hot) ----
    float pa0 = 0.f, pa1 = 0.f, pa2 = 0.f, pa3 = 0.f;
    {
        int cnt = 0;
#pragma unroll
        for (int t = 0; t < 7; ++t) {
            const float* tab = (t == 0) ? e0 : (t == 1) ? e1 : (t == 2) ? e2
                             : (t == 3) ? e3 : (t == 4) ? e4 : (t == 5) ? e5 : e6;
#pragma unroll
            for (int v = 0; v < CARD[t]; ++v) {
                const int i = OFFB[t] + v;               // compile-time
                const float f = (i < 64) ? rdlane(wA, i) : rdlane(wB, i - 64);
                const float ev = tab[v * 64 + l];
                if ((cnt & 3) == 0)      pa0 = fmaf(f, ev, pa0);
                else if ((cnt & 3) == 1) pa1 = fmaf(f, ev, pa1);
                else if ((cnt & 3) == 2) pa2 = fmaf(f, ev, pa2);
                else                     pa3 = fmaf(f, ev, pa3);
                ++cnt;
            }
        }
    }
    // pooled cat dim l -> padded pooled LDS slot l
    pls[l + (l >> 5)] = (pa0 + pa1) + (pa2 + pa3);

    // ---- W1: 4-slice x 16-col-group dwordx4 scheme ----
    // lane (s,q): cols 4q..4q+3, rows d = 32s..32s+31.
    const int qg = lo16;            // col group
    const int sl = l >> 4;          // row slice
    float hb0, hb1, hb2, hb3;
    {
        const flt4a b14 = *(const flt4a*)(b1 + 4 * qg);
        const bool iss0 = (sl == 0);
        hb0 = iss0 ? b14.x : 0.f;
        hb1 = iss0 ? b14.y : 0.f;
        hb2 = iss0 ? b14.z : 0.f;
        hb3 = iss0 ? b14.w : 0.f;
    }
#pragma unroll
    for (int i = 0; i < 32; ++i) {
        const int d = sl * 32 + i;
        const float f = pls[d + sl];                 // (d>>5)==sl, conflict-free
        const flt4a wv = *(const flt4a*)(W1 + d * 64 + 4 * qg);
        hb0 = fmaf(f, wv.x, hb0);
        hb1 = fmaf(f, wv.y, hb1);
        hb2 = fmaf(f, wv.z, hb2);
        hb3 = fmaf(f, wv.w, hb3);
    }
    // reduce over slices -> every lane holds h for cols 4q..4q+3
    hb0 += __shfl_xor(hb0, 16); hb0 += __shfl_xor(hb0, 32);
    hb1 += __shfl_xor(hb1, 16); hb1 += __shfl_xor(hb1, 32);
    hb2 += __shfl_xor(hb2, 16); hb2 += __shfl_xor(hb2, 32);
    hb3 += __shfl_xor(hb3, 16); hb3 += __shfl_xor(hb3, 32);
    const float h0 = fmaxf(hb0, 0.f);
    const float h1 = fmaxf(hb1, 0.f);
    const float h2 = fmaxf(hb2, 0.f);
    const float h3 = fmaxf(hb3, 0.f);

    // ---- W2: rows 4q..4q+3 (8 floats), partial then butterfly over q ----
    const flt4a w2a = *(const flt4a*)(W2 + 8 * qg);      // rows 4q,4q+1
    const flt4a w2b = *(const flt4a*)(W2 + 8 * qg + 4);  // rows 4q+2,4q+3
    float rr0 = h0 * w2a.x + h1 * w2a.z + h2 * w2b.x + h3 * w2b.z;
    float rr1 = h0 * w2a.y + h1 * w2a.w + h2 * w2b.y + h3 * w2b.w;
#pragma unroll
    for (int off = 1; off <= 8; off <<= 1) {
        rr0 += __shfl_xor(rr0, off);
        rr1 += __shfl_xor(rr1, off);
    }
    if (l == 0) {
        const float2 bb2 = *(const float2*)b2;
        float2 res;
        res.x = fmaxf(rr0 + bb2.x, 0.f);
        res.y = fmaxf(rr1 + bb2.y, 0.f);
        ((float2*)out)[b] = res;
    }
}

extern "C" void kernel_launch(void* const* d_in, const int* in_sizes, int n_in,
                              void* d_out, int out_size, void* d_ws, size_t ws_size,
                              hipStream_t stream)
{
    const float* cont_x = (const float*)d_in[0];
    const int*   cat_x  = (const int*)d_in[1];
    const int*   length = (const int*)d_in[2];
    const float* e0     = (const float*)d_in[3];
    const float* e1     = (const float*)d_in[4];
    const float* e2     = (const float*)d_in[5];
    const float* e3     = (const float*)d_in[6];
    const float* e4     = (const float*)d_in[7];
    const float* e5     = (const float*)d_in[8];
    const float* e6     = (const float*)d_in[9];
    const float* W_cont = (const float*)d_in[10];
    const float* b_cont = (const float*)d_in[11];
    const float* W1     = (const float*)d_in[12];
    const float* b1     = (const float*)d_in[13];
    const float* W2     = (const float*)d_in[14];
    const float* b2     = (const float*)d_in[15];
    float*       out    = (float*)d_out;

    const int B = in_sizes[2];                 // 2048
    const int S = in_sizes[0] / (B * 5);       // 512

    hipLaunchKernelGGL(mlp_wave, dim3(B), dim3(64), 0, stream,
                       cont_x, cat_x, length,
                       e0, e1, e2, e3, e4, e5, e6,
                       W_cont, b_cont, W1, b1, W2, b2,
                       out, S);
}